// Round 12
// baseline (708.602 us; speedup 1.0000x reference)
//
#include <hip/hip_runtime.h>
#include <cstdint>
#include <cstddef>

typedef __attribute__((ext_vector_type(8))) short short8;
typedef __attribute__((ext_vector_type(4))) short short4v;
typedef __attribute__((ext_vector_type(8))) __bf16 bf16x8;
typedef __attribute__((ext_vector_type(4))) float f32x4;
typedef unsigned short u16;

static constexpr int Bb = 32, Nn = 4096, NSs = 16, Dd = 512, Hh = 8, DFF = 2048;
static constexpr float SCALE = 0.125f;   // (64)^-0.5
static constexpr float EPSR  = 1e-8f;
static constexpr float LN_EPS = 1e-5f;
static constexpr int JS = 16;            // j-splits in attn_f

__device__ __forceinline__ u16 f2b(float x) {
  union { float f; uint32_t u; } a; a.f = x;
  uint32_t r = a.u + 0x7fffu + ((a.u >> 16) & 1u);
  return (u16)(r >> 16);
}
__device__ __forceinline__ float b2f(u16 x) {
  union { uint32_t u; float f; } a; a.u = ((uint32_t)x) << 16; return a.f;
}

__device__ __forceinline__ f32x4 mfma16(short8 a, short8 b, f32x4 c) {
  return __builtin_amdgcn_mfma_f32_16x16x32_bf16(
      __builtin_bit_cast(bf16x8, a), __builtin_bit_cast(bf16x8, b), c, 0, 0, 0);
}

// async global->LDS, 16B per lane; LDS dest must be wave-uniform base (+lane*16 HW)
__device__ __forceinline__ void gload16(const u16* g, u16* l) {
  __builtin_amdgcn_global_load_lds(
      (const __attribute__((address_space(1))) void*)g,
      (__attribute__((address_space(3))) void*)l, 16, 0, 0);
}

// ---------------- LayerNorm rows: fp32 [R,512] -> bf16 [R,512] ----------------
__global__ __launch_bounds__(256) void ln_rows(const float* __restrict__ src,
    const float* __restrict__ g, const float* __restrict__ bt,
    u16* __restrict__ dst, int R) {
  int row = blockIdx.x * 4 + (threadIdx.x >> 6);
  if (row >= R) return;
  int lane = threadIdx.x & 63;
  const float* p = src + (size_t)row * Dd + lane * 8;
  float4 u0 = *(const float4*)p;
  float4 u1 = *(const float4*)(p + 4);
  float x[8] = {u0.x,u0.y,u0.z,u0.w,u1.x,u1.y,u1.z,u1.w};
  float s = 0.f, s2 = 0.f;
#pragma unroll
  for (int e = 0; e < 8; ++e) { s += x[e]; s2 += x[e]*x[e]; }
#pragma unroll
  for (int m = 1; m < 64; m <<= 1) { s += __shfl_xor(s, m); s2 += __shfl_xor(s2, m); }
  float mean = s * (1.f/512.f);
  float var  = s2 * (1.f/512.f) - mean*mean;
  float rstd = rsqrtf(var + LN_EPS);
  union { u16 o[8]; short8 v; } ou;
#pragma unroll
  for (int e = 0; e < 8; ++e)
    ou.o[e] = f2b((x[e]-mean)*rstd*g[lane*8+e] + bt[lane*8+e]);
  *(short8*)(dst + (size_t)row * Dd + lane * 8) = ou.v;
}

// ---------------- fused K/V GEMM 128x128, BK=64 single-buffer ----------------
// Epilogue fix (R12): ak is computed with SWAPPED operands mfma(kf, af) so a
// lane holds one Ck row (li) x 4 consecutive cols (lk*4+r) -> single packed
// 8B store per acc. av keeps mfma(af, vf): 4 consecutive rows of one col =
// 8B packed in CvT's [col][row] layout. Epilogue: 80 -> 32 stores/thread
// (was 64 scalar 2B Ck stores -- the schedule-invariant cost of R1-R11).
__global__ __launch_bounds__(256, 2) void gemm_kv(const u16* __restrict__ A,
    const u16* __restrict__ Bk, const u16* __restrict__ Bv,
    u16* __restrict__ Ck, u16* __restrict__ CvT) {
  __shared__ u16 lA[128*64];
  __shared__ u16 lK[128*64];
  __shared__ u16 lV[128*64];
  const int tid = threadIdx.x, lane = tid & 63, wid = tid >> 6;
  const int wr = wid >> 1, wc = wid & 1;
  const int n  = blockIdx.y * 4 + blockIdx.x;
  const int orig = (n & 7) * 512 + (n >> 3);
  const int bm = (orig >> 2) * 128, bn = (orig & 3) * 128;
  const size_t BN = (size_t)Bb * Nn;
  f32x4 ak[4][4] = {};   // ak[m][nn]: D rows = K-cols (lk*4+r), D cols = A-rows (li)
  f32x4 av[4][4] = {};   // av[m][nn]: D rows = A-rows (lk*4+r), D cols = V-cols (li)
  const int sr = lane >> 3;
  const int ss = ((lane & 7) ^ (sr & 7)) * 8;   // swizzled source col (u16)
  const int li = lane & 15, lk = lane >> 4;
  const int sx = (li & 7) * 8;                  // read-side XOR (u16 units)
  for (int t = 0; t < 8; ++t) {
    const int k0 = t * 64;
    __syncthreads();
#pragma unroll
    for (int gi = 0; gi < 4; ++gi) {
      const int rb = wid * 32 + gi * 8;
      gload16(A  + (size_t)(bm + rb + sr) * Dd + k0 + ss, &lA[rb * 64]);
      gload16(Bk + (size_t)(bn + rb + sr) * Dd + k0 + ss, &lK[rb * 64]);
      gload16(Bv + (size_t)(bn + rb + sr) * Dd + k0 + ss, &lV[rb * 64]);
    }
    __syncthreads();
#pragma unroll
    for (int kk = 0; kk < 2; ++kk) {
      const int cs = ((kk * 4 + lk) * 8) ^ sx;
      short8 af[4], kf[4], vf[4];
#pragma unroll
      for (int m = 0; m < 4; ++m)
        af[m] = *(const short8*)&lA[(wr*64 + m*16 + li)*64 + cs];
#pragma unroll
      for (int nn2 = 0; nn2 < 4; ++nn2) {
        kf[nn2] = *(const short8*)&lK[(wc*64 + nn2*16 + li)*64 + cs];
        vf[nn2] = *(const short8*)&lV[(wc*64 + nn2*16 + li)*64 + cs];
      }
#pragma unroll
      for (int m = 0; m < 4; ++m)
#pragma unroll
        for (int nn2 = 0; nn2 < 4; ++nn2) {
          ak[m][nn2] = mfma16(kf[nn2], af[m], ak[m][nn2]);   // swapped
          av[m][nn2] = mfma16(af[m], vf[nn2], av[m][nn2]);
        }
    }
  }
#pragma unroll
  for (int m = 0; m < 4; ++m)
#pragma unroll
    for (int nn2 = 0; nn2 < 4; ++nn2) {
      // Ck: lane holds row (bm+wr*64+m*16+li), cols c0..c0+3
      {
        int row = bm + wr*64 + m*16 + li;
        int c0  = bn + wc*64 + nn2*16 + lk*4;
        f32x4 vk = ak[m][nn2];
        union { u16 o[4]; short4v v4; } ou;
#pragma unroll
        for (int r = 0; r < 4; ++r) ou.o[r] = f2b(vk[r]);
        *(short4v*)&Ck[(size_t)row * Dd + c0] = ou.v4;
      }
      // CvT: lane holds col (bn+wc*64+nn2*16+li), rows r0..r0+3
      {
        int col = bn + wc*64 + nn2*16 + li;
        int r0  = bm + wr*64 + m*16 + lk*4;
        f32x4 vv = av[m][nn2];
        union { u16 o[4]; short4v v4; } ou;
#pragma unroll
        for (int r = 0; r < 4; ++r) ou.o[r] = f2b(vv[r]);
        *(short4v*)&CvT[(size_t)col * BN + r0] = ou.v4;
      }
    }
}

// ---------------- GEMM 64x64 (small M): operands from global, packed epilogue
// acc = mfma(bf, af): lane holds one row (li) x 4 consecutive cols (lk*4+r)
// -> packed 8B (bf16) / 16B (f32) stores.
// EP: 0 = bf16 out; 1 = f32 out + residual; 2 = bf16 out + bias + relu;
//     3 = f32 out + bias + residual
template<int EP>
__global__ __launch_bounds__(256) void gemm64(const u16* __restrict__ A,
    const u16* __restrict__ Bw, void* __restrict__ Cp,
    const float* __restrict__ bias, const float* __restrict__ res,
    int N, int K) {
  const int lane = threadIdx.x & 63, wid = threadIdx.x >> 6;
  const int wr = wid >> 1, wc = wid & 1;
  const int bm = blockIdx.y * 64, bn = blockIdx.x * 64;
  const int li = lane & 15, lk = lane >> 4;
  f32x4 acc[2][2] = {};
  const u16* Ap = A  + (size_t)(bm + wr*32 + li) * K + lk*8;
  const u16* Bp = Bw + (size_t)(bn + wc*32 + li) * K + lk*8;
#pragma unroll 4
  for (int k0 = 0; k0 < K; k0 += 32) {
    short8 af[2], bf[2];
    af[0] = *(const short8*)(Ap + k0);
    af[1] = *(const short8*)(Ap + (size_t)16*K + k0);
    bf[0] = *(const short8*)(Bp + k0);
    bf[1] = *(const short8*)(Bp + (size_t)16*K + k0);
#pragma unroll
    for (int m = 0; m < 2; ++m)
#pragma unroll
      for (int nn2 = 0; nn2 < 2; ++nn2)
        acc[m][nn2] = mfma16(bf[nn2], af[m], acc[m][nn2]);   // swapped
  }
#pragma unroll
  for (int m = 0; m < 2; ++m)
#pragma unroll
    for (int nn2 = 0; nn2 < 2; ++nn2) {
      int row = bm + wr*32 + m*16 + li;
      int c0  = bn + wc*32 + nn2*16 + lk*4;
      size_t off = (size_t)row * N + c0;
      f32x4 v = acc[m][nn2];
      if constexpr (EP == 0) {
        union { u16 o[4]; short4v v4; } ou;
#pragma unroll
        for (int r = 0; r < 4; ++r) ou.o[r] = f2b(v[r]);
        *(short4v*)&((u16*)Cp)[off] = ou.v4;
      } else if constexpr (EP == 1) {
        float4 rr = *(const float4*)&res[off];
        float4 o = {v[0] + rr.x, v[1] + rr.y, v[2] + rr.z, v[3] + rr.w};
        *(float4*)&((float*)Cp)[off] = o;
      } else if constexpr (EP == 2) {
        float4 bb = *(const float4*)&bias[c0];
        union { u16 o[4]; short4v v4; } ou;
        float x0 = v[0] + bb.x, x1 = v[1] + bb.y, x2 = v[2] + bb.z, x3 = v[3] + bb.w;
        ou.o[0] = f2b(x0 > 0.f ? x0 : 0.f); ou.o[1] = f2b(x1 > 0.f ? x1 : 0.f);
        ou.o[2] = f2b(x2 > 0.f ? x2 : 0.f); ou.o[3] = f2b(x3 > 0.f ? x3 : 0.f);
        *(short4v*)&((u16*)Cp)[off] = ou.v4;
      } else {
        float4 bb = *(const float4*)&bias[c0];
        float4 rr = *(const float4*)&res[off];
        float4 o = {v[0] + bb.x + rr.x, v[1] + bb.y + rr.y,
                    v[2] + bb.z + rr.z, v[3] + bb.w + rr.w};
        *(float4*)&((float*)Cp)[off] = o;
      }
    }
}

// ---------------- FUSED attention v2: register softmax, 2 blocks/CU ----------
// grid (JS=16 j-splits, B); 512 thr = 8 waves, wave = head. Per 64-j tile:
// dots in registers -> column max/sum via shfl(lk) + redM/redS[8][64] cross-
// wave -> P bf16 into P2[8][16][72] (wave-local consumption) -> PV MFMA with
// swapped operands (vb, pa): lane holds one i (li) x 4 consecutive d -> Tout
// written as float4 (was 16 scattered dwords).
__global__ __launch_bounds__(512, 4) void attn_f(const u16* __restrict__ q,
    const u16* __restrict__ kk, const u16* __restrict__ vT,
    float* __restrict__ rowsum, float* __restrict__ Tpart,
    float* __restrict__ attn_mean) {
  const int js = blockIdx.x, b = blockIdx.y;
  const int tid = threadIdx.x, lane = tid & 63, h = tid >> 6;
  __shared__ float redM[8][64];
  __shared__ float redS[8][64];
  __shared__ u16 P2[8][16][72];
  const int li = lane & 15, lk = lane >> 4;
  const size_t BN = (size_t)Bb * Nn;
  const u16* qb = q + (((size_t)b*16 + li)*8 + h)*64 + lk*8;
  short8 a0 = *(const short8*)qb;
  short8 a1 = *(const short8*)(qb + 32);
  f32x4 apv[4] = {};   // apv[n]: D rows = d (n*16+lk*4+r), D cols = i (li)
  float rs_acc[4] = {0.f, 0.f, 0.f, 0.f};
  for (int t2 = 0; t2 < 4; ++t2) {
    const int j0 = js * 256 + t2 * 64;
    // ---- dots in registers: dt[n][r] = dots[j=n*16+li][ih=(lk*4+r)*8+h] ----
    f32x4 dt[4];
#pragma unroll
    for (int n = 0; n < 4; ++n) {
      const u16* kb = kk + ((size_t)b*Nn + j0 + n*16 + li)*Dd + h*64 + lk*8;
      f32x4 acc = {};
      acc = mfma16(a0, *(const short8*)kb, acc);
      acc = mfma16(a1, *(const short8*)(kb + 32), acc);
#pragma unroll
      for (int r = 0; r < 4; ++r) dt[n][r] = acc[r] * SCALE;
    }
    // ---- wave-local column max (reduce r in-lane, lk via shfl) ----
#pragma unroll
    for (int n = 0; n < 4; ++n) {
      float v = fmaxf(fmaxf(dt[n][0], dt[n][1]), fmaxf(dt[n][2], dt[n][3]));
      v = fmaxf(v, __shfl_xor(v, 16));
      v = fmaxf(v, __shfl_xor(v, 32));
      if (lk == 0) redM[h][n*16 + li] = v;
    }
    __syncthreads();                       // redM complete (s1)
    float M[4];
#pragma unroll
    for (int n = 0; n < 4; ++n) {
      float m2 = redM[0][n*16 + li];
#pragma unroll
      for (int p = 1; p < 8; ++p) m2 = fmaxf(m2, redM[p][n*16 + li]);
      M[n] = m2;
    }
    // ---- exp + wave-local column sum ----
#pragma unroll
    for (int n = 0; n < 4; ++n) {
      float s = 0.f;
#pragma unroll
      for (int r = 0; r < 4; ++r) { dt[n][r] = __expf(dt[n][r] - M[n]); s += dt[n][r]; }
      s += __shfl_xor(s, 16);
      s += __shfl_xor(s, 32);
      if (lk == 0) redS[h][n*16 + li] = s;
    }
    __syncthreads();                       // redS complete (s2); redM reads done
#pragma unroll
    for (int n = 0; n < 4; ++n) {
      float s2 = redS[0][n*16 + li];
#pragma unroll
      for (int p = 1; p < 8; ++p) s2 += redS[p][n*16 + li];
      float inv = 1.f / s2;
#pragma unroll
      for (int r = 0; r < 4; ++r) dt[n][r] = dt[n][r] * inv + EPSR;  // attn+EPS
    }
    // ---- P -> LDS bf16 (consumed by SAME wave in PV; no barrier needed) ----
#pragma unroll
    for (int n = 0; n < 4; ++n)
#pragma unroll
      for (int r = 0; r < 4; ++r)
        P2[h][lk*4 + r][n*16 + li] = f2b(dt[n][r]);
    // ---- rowsum partials: sum over j (n in-lane, li via shfl) ----
#pragma unroll
    for (int r = 0; r < 4; ++r) {
      float v = dt[0][r] + dt[1][r] + dt[2][r] + dt[3][r];
      v += __shfl_xor(v, 1); v += __shfl_xor(v, 2);
      v += __shfl_xor(v, 4); v += __shfl_xor(v, 8);
      rs_acc[r] += v;                      // li==0 lanes hold column-group sum
    }
    // ---- PV: apv[n] += V_h[d][j] * P_h[i][j]  (swapped: rows=d, cols=i) ----
    short8 pa0 = *(const short8*)&P2[h][li][lk*8];
    short8 pa1 = *(const short8*)&P2[h][li][32 + lk*8];
#pragma unroll
    for (int n = 0; n < 4; ++n) {
      const u16* vb = vT + (size_t)(h*64 + n*16 + li)*BN + (size_t)b*Nn + j0 + lk*8;
      apv[n] = mfma16(*(const short8*)vb, pa0, apv[n]);
      apv[n] = mfma16(*(const short8*)(vb + 32), pa1, apv[n]);
    }
    // ---- attn_mean (last iteration only): cross-wave read of P2 ----
    if (attn_mean != nullptr) {
      __syncthreads();                     // all P2 writes visible
      int j = tid & 63;
#pragma unroll
      for (int ii = 0; ii < 2; ++ii) {
        int i = (tid >> 6) + ii*8;
        float sm = 0.f;
#pragma unroll
        for (int hh = 0; hh < 8; ++hh) sm += b2f(P2[hh][i][j]);
        attn_mean[((size_t)b*16 + i)*Nn + j0 + j] = sm * 0.125f - EPSR;
      }
      __syncthreads();                     // reads done before next-tile writes
    }
  }
  // Tout[i][d]: lane holds i=li, d = n*16+lk*4..+3 -> packed float4
  float* Tout = Tpart + (((size_t)js * Bb + b) * 8 + h) * 16 * 64;
#pragma unroll
  for (int n = 0; n < 4; ++n) {
    float4 o = {apv[n][0], apv[n][1], apv[n][2], apv[n][3]};
    *(float4*)&Tout[(size_t)li * 64 + n*16 + lk*4] = o;
  }
  if (li == 0)
#pragma unroll
    for (int r = 0; r < 4; ++r)
      atomicAdd(&rowsum[b*128 + (lk*4 + r)*8 + h], rs_acc[r]);
}

// combine partials + renormalize: updb[(b*16+i)*512 + h*64+d]
__global__ void upd_c(const float* __restrict__ Tpart,
    const float* __restrict__ rs, u16* __restrict__ updb) {
  int idx = blockIdx.x * 256 + threadIdx.x;   // 262144 total
  int o = idx & 511, bi = idx >> 9;
  int b = bi >> 4, i = bi & 15;
  int h = o >> 6, d = o & 63;
  size_t base = (((size_t)b * 8 + h) * 16 + i) * 64 + d;
  const size_t stride = (size_t)Bb * 8 * 16 * 64;
  float t = 0.f;
#pragma unroll
  for (int p = 0; p < JS; ++p) t += Tpart[base + p * stride];
  updb[idx] = f2b(t / rs[b * 128 + i * 8 + h]);
}

// ---------------- small utility kernels --------------------------------------
__global__ void cvt_w(const float* __restrict__ s, u16* __restrict__ d, int n) {
  int i = blockIdx.x*256 + threadIdx.x;
  if (i < n) d[i] = f2b(s[i]);
}
// tiled transpose+convert: d[C][R] = bf16(s[R][C]^T)
__global__ __launch_bounds__(256) void tr_cvt(const float* __restrict__ s,
    u16* __restrict__ d, int R, int C) {
  __shared__ u16 t[32][33];
  const int c0 = blockIdx.x*32, r0 = blockIdx.y*32;
  const int tr = threadIdx.x >> 3, tc4 = (threadIdx.x & 7)*4;
  float4 v = *(const float4*)&s[(size_t)(r0+tr)*C + c0 + tc4];
  t[tr][tc4+0] = f2b(v.x); t[tr][tc4+1] = f2b(v.y);
  t[tr][tc4+2] = f2b(v.z); t[tr][tc4+3] = f2b(v.w);
  __syncthreads();
  const int oc = threadIdx.x >> 3, or4 = (threadIdx.x & 7)*4;
  union { u16 o[4]; short4v v4; } ou;
#pragma unroll
  for (int e = 0; e < 4; ++e) ou.o[e] = t[or4+e][oc];
  *(short4v*)&d[(size_t)(c0+oc)*R + r0 + or4] = ou.v4;
}
__global__ void copy_f32v4(const float* __restrict__ s, float* __restrict__ d, int n4) {
  int i = blockIdx.x*256 + threadIdx.x;
  if (i < n4) ((float4*)d)[i] = ((const float4*)s)[i];
}

extern "C" void kernel_launch(void* const* d_in, const int* in_sizes, int n_in,
                              void* d_out, int out_size, void* d_ws, size_t ws_size,
                              hipStream_t stream) {
  (void)in_sizes; (void)n_in; (void)out_size; (void)ws_size;
  const float* inputs  = (const float*)d_in[0];
  const float* cond    = (const float*)d_in[1];
  const float* ln_in_g = (const float*)d_in[2];
  const float* ln_in_b = (const float*)d_in[3];
  const float* Wk = (const float*)d_in[4];
  const float* Wv = (const float*)d_in[5];
  const float* Wq = (const float*)d_in[6];
  const float* Wo = (const float*)d_in[7];
  const float* ln_s_g = (const float*)d_in[8];
  const float* ln_s_b = (const float*)d_in[9];
  const float* ln_f_g = (const float*)d_in[10];
  const float* ln_f_b = (const float*)d_in[11];
  const float* W1 = (const float*)d_in[12];
  const float* b1 = (const float*)d_in[13];
  const float* W2 = (const float*)d_in[14];
  const float* b2 = (const float*)d_in[15];
  float* out_slots = (float*)d_out;
  float* out_amean = (float*)d_out + (size_t)Bb*NSs*Dd;

  char* w = (char*)d_ws;
  auto alloc = [&](size_t bytes) {
    char* p = w; w += (bytes + 255) & ~(size_t)255; return p;
  };
  u16*  xn    = (u16*)alloc((size_t)Bb*Nn*Dd*2);
  u16*  kbuf  = (u16*)alloc((size_t)Bb*Nn*Dd*2);
  u16*  vT    = (u16*)alloc((size_t)Bb*Nn*Dd*2);   // [512][B*N]
  float* Tpart = (float*)alloc((size_t)JS*Bb*8*16*64*4);  // [js][b][h][i][d]
  float* slots = (float*)alloc((size_t)Bb*NSs*Dd*4);
  u16*  qb    = (u16*)alloc((size_t)Bb*NSs*Dd*2);
  u16*  snb   = (u16*)alloc((size_t)Bb*NSs*Dd*2);
  u16*  s2nb  = (u16*)alloc((size_t)Bb*NSs*Dd*2);
  u16*  h1b   = (u16*)alloc((size_t)Bb*NSs*DFF*2);
  u16*  updb  = (u16*)alloc((size_t)Bb*NSs*Dd*2);
  float* rowsum = (float*)alloc((size_t)Bb*128*3*4);   // one per iteration
  u16*  wkb = (u16*)alloc(262144*2);
  u16*  wvb = (u16*)alloc(262144*2);
  u16*  wqb = (u16*)alloc(262144*2);
  u16*  wob = (u16*)alloc(262144*2);
  u16*  w1t = (u16*)alloc((size_t)1048576*2);
  u16*  w2t = (u16*)alloc((size_t)1048576*2);

  // weights -> bf16 (W1/W2 transposed so B-operand is [out,K] row-major)
  cvt_w<<<1024, 256, 0, stream>>>(Wk, wkb, 262144);
  cvt_w<<<1024, 256, 0, stream>>>(Wv, wvb, 262144);
  cvt_w<<<1024, 256, 0, stream>>>(Wq, wqb, 262144);
  cvt_w<<<1024, 256, 0, stream>>>(Wo, wob, 262144);
  tr_cvt<<<dim3(64, 16), 256, 0, stream>>>(W1, w1t, 512, 2048);
  tr_cvt<<<dim3(16, 64), 256, 0, stream>>>(W2, w2t, 2048, 512);
  // slots <- conditioning; rowsum <- 0 (all 3 iterations)
  copy_f32v4<<<256, 256, 0, stream>>>(cond, slots, 65536);
  (void)hipMemsetAsync(rowsum, 0, (size_t)Bb*128*3*4, stream);
  // x = LN(inputs) -> bf16
  ln_rows<<<Bb*Nn/4, 256, 0, stream>>>(inputs, ln_in_g, ln_in_b, xn, Bb*Nn);
  // fused: k = x @ Wk^T  [B*N,512]  and  vT = (x @ Wv^T)^T  [512, B*N]
  gemm_kv<<<dim3(4, Bb*Nn/128), 256, 0, stream>>>(xn, wkb, wvb, kbuf, vT);

  for (int it = 0; it < 3; ++it) {
    float* rsp = rowsum + (size_t)it * Bb * 128;
    ln_rows<<<128, 256, 0, stream>>>(slots, ln_s_g, ln_s_b, snb, Bb*NSs);
    gemm64<0><<<dim3(8, 8), 256, 0, stream>>>(snb, wqb, qb, nullptr, nullptr, 512, 512);
    attn_f<<<dim3(JS, Bb), 512, 0, stream>>>(qb, kbuf, vT, rsp, Tpart,
                                             it == 2 ? out_amean : nullptr);
    upd_c<<<1024, 256, 0, stream>>>(Tpart, rsp, updb);
    gemm64<1><<<dim3(8, 8), 256, 0, stream>>>(updb, wob, slots, nullptr, slots, 512, 512);
    ln_rows<<<128, 256, 0, stream>>>(slots, ln_f_g, ln_f_b, s2nb, Bb*NSs);
    gemm64<2><<<dim3(32, 8), 256, 0, stream>>>(s2nb, w1t, h1b, b1, nullptr, 2048, 512);
    gemm64<3><<<dim3(8, 8), 256, 0, stream>>>(h1b, w2t, slots, b2, slots, 512, 2048);
  }
  copy_f32v4<<<256, 256, 0, stream>>>(slots, out_slots, 65536);
}

// Round 13
// 700.078 us; speedup vs baseline: 1.0122x; 1.0122x over previous
//
#include <hip/hip_runtime.h>
#include <cstdint>
#include <cstddef>

typedef __attribute__((ext_vector_type(8))) short short8;
typedef __attribute__((ext_vector_type(4))) short short4v;
typedef __attribute__((ext_vector_type(8))) __bf16 bf16x8;
typedef __attribute__((ext_vector_type(4))) float f32x4;
typedef unsigned short u16;

static constexpr int Bb = 32, Nn = 4096, NSs = 16, Dd = 512, Hh = 8, DFF = 2048;
static constexpr float SCALE = 0.125f;   // (64)^-0.5
static constexpr float EPSR  = 1e-8f;
static constexpr float LN_EPS = 1e-5f;
static constexpr int JS = 16;            // j-splits in attn_f

__device__ __forceinline__ u16 f2b(float x) {
  union { float f; uint32_t u; } a; a.f = x;
  uint32_t r = a.u + 0x7fffu + ((a.u >> 16) & 1u);
  return (u16)(r >> 16);
}
__device__ __forceinline__ float b2f(u16 x) {
  union { uint32_t u; float f; } a; a.u = ((uint32_t)x) << 16; return a.f;
}

__device__ __forceinline__ f32x4 mfma16(short8 a, short8 b, f32x4 c) {
  return __builtin_amdgcn_mfma_f32_16x16x32_bf16(
      __builtin_bit_cast(bf16x8, a), __builtin_bit_cast(bf16x8, b), c, 0, 0, 0);
}

// async global->LDS, 16B per lane; LDS dest must be wave-uniform base (+lane*16 HW)
__device__ __forceinline__ void gload16(const u16* g, u16* l) {
  __builtin_amdgcn_global_load_lds(
      (const __attribute__((address_space(1))) void*)g,
      (__attribute__((address_space(3))) void*)l, 16, 0, 0);
}

// ---------------- LayerNorm rows: fp32 [R,512] -> bf16 [R,512] ----------------
__global__ __launch_bounds__(256) void ln_rows(const float* __restrict__ src,
    const float* __restrict__ g, const float* __restrict__ bt,
    u16* __restrict__ dst, int R) {
  int row = blockIdx.x * 4 + (threadIdx.x >> 6);
  if (row >= R) return;
  int lane = threadIdx.x & 63;
  const float* p = src + (size_t)row * Dd + lane * 8;
  float4 u0 = *(const float4*)p;
  float4 u1 = *(const float4*)(p + 4);
  float x[8] = {u0.x,u0.y,u0.z,u0.w,u1.x,u1.y,u1.z,u1.w};
  float s = 0.f, s2 = 0.f;
#pragma unroll
  for (int e = 0; e < 8; ++e) { s += x[e]; s2 += x[e]*x[e]; }
#pragma unroll
  for (int m = 1; m < 64; m <<= 1) { s += __shfl_xor(s, m); s2 += __shfl_xor(s2, m); }
  float mean = s * (1.f/512.f);
  float var  = s2 * (1.f/512.f) - mean*mean;
  float rstd = rsqrtf(var + LN_EPS);
  union { u16 o[8]; short8 v; } ou;
#pragma unroll
  for (int e = 0; e < 8; ++e)
    ou.o[e] = f2b((x[e]-mean)*rstd*g[lane*8+e] + bt[lane*8+e]);
  *(short8*)(dst + (size_t)row * Dd + lane * 8) = ou.v;
}

// ---------------- fused K/V GEMM: 8-PHASE pipeline (T3+T4+T5, m201 port) -----
// BM=256 x BN=128 (per array), BK=64, 8 waves (wr 0..1 x wn 0..3), 512 thr.
// LDS 128KB: dbuf x {A[256][64] 32K, Wk[128][64] 16K, Wv[128][64] 16K}.
// 4 phases per K-tile, each {ds-read subtile || stage 1 half-tile -> barrier
// -> lgkmcnt(0) -> setprio(1) 16 MFMA setprio(0) -> barrier}. Stage targets
// K-tile t+1's units {Ah0,Ah1,Wk,Wv} into buf[t+1&1] (freed at t-1's end).
// COUNTED vmcnt(2): end-ph0 (drains current Wv for ph1) and end-ph3 (drains
// t+1's Ah0/Ah1/Wk for next ph0). Never vmcnt(0) in steady state.
// Swizzle: LDS[r][s16]=G[r][s16^(r&7)] via pre-swizzled source (R6: 0 confl).
__global__ __launch_bounds__(512, 2) void gemm_kv(const u16* __restrict__ A,
    const u16* __restrict__ Bk, const u16* __restrict__ Bv,
    u16* __restrict__ Ck, u16* __restrict__ CvT) {
  __shared__ u16 lA[2][256*64];
  __shared__ u16 lK[2][128*64];
  __shared__ u16 lV[2][128*64];
  const int tid = threadIdx.x, lane = tid & 63, wid = tid >> 6;
  const int wr = wid >> 2, wn = wid & 3;       // 2 M-halves x 4 N-quarters
  // bijective XCD swizzle: nwg=2048 = 8 XCDs x 256; 4 N-blocks of one
  // A-panel are consecutive -> same XCD L2.
  const int n = blockIdx.x;
  const int orig = (n & 7) * 256 + (n >> 3);
  const int bm = (orig >> 2) * 256, bn = (orig & 3) * 128;
  const size_t BN = (size_t)Bb * Nn;
  f32x4 ak[8][2] = {};
  f32x4 av[8][2] = {};
  const int sr = lane >> 3;
  const int ss = ((lane & 7) ^ (sr & 7)) * 8;  // inverse-swizzled source slot
  const int li = lane & 15, lk = lane >> 4;
#define STG_A(buf, tt, h) do { \
    gload16(A + (size_t)(bm + (h)*128 + wid*16 + sr) * Dd + (tt)*64 + ss, \
            &lA[buf][((h)*128 + wid*16) * 64]); \
    gload16(A + (size_t)(bm + (h)*128 + wid*16 + 8 + sr) * Dd + (tt)*64 + ss, \
            &lA[buf][((h)*128 + wid*16 + 8) * 64]); \
  } while (0)
#define STG_K(buf, tt) do { \
    gload16(Bk + (size_t)(bn + wid*16 + sr) * Dd + (tt)*64 + ss, \
            &lK[buf][(wid*16) * 64]); \
    gload16(Bk + (size_t)(bn + wid*16 + 8 + sr) * Dd + (tt)*64 + ss, \
            &lK[buf][(wid*16 + 8) * 64]); \
  } while (0)
#define STG_V(buf, tt) do { \
    gload16(Bv + (size_t)(bn + wid*16 + sr) * Dd + (tt)*64 + ss, \
            &lV[buf][(wid*16) * 64]); \
    gload16(Bv + (size_t)(bn + wid*16 + 8 + sr) * Dd + (tt)*64 + ss, \
            &lV[buf][(wid*16 + 8) * 64]); \
  } while (0)
#define PH_ENTER() do { \
    __builtin_amdgcn_sched_barrier(0); \
    __builtin_amdgcn_s_barrier(); \
    asm volatile("s_waitcnt lgkmcnt(0)" ::: "memory"); \
    __builtin_amdgcn_sched_barrier(0); \
    __builtin_amdgcn_s_setprio(1); \
  } while (0)
#define PH_EXIT() do { \
    __builtin_amdgcn_s_setprio(0); \
    __builtin_amdgcn_sched_barrier(0); \
    __builtin_amdgcn_s_barrier(); \
    __builtin_amdgcn_sched_barrier(0); \
  } while (0)
#define PH_EXIT_VM(nvm) do { \
    __builtin_amdgcn_s_setprio(0); \
    __builtin_amdgcn_sched_barrier(0); \
    if (nvm) asm volatile("s_waitcnt vmcnt(2)" ::: "memory"); \
    else     asm volatile("s_waitcnt vmcnt(0)" ::: "memory"); \
    __builtin_amdgcn_sched_barrier(0); \
    __builtin_amdgcn_s_barrier(); \
    __builtin_amdgcn_sched_barrier(0); \
  } while (0)
  // prologue: stage K-tile 0 (4 units); need Ah0,Ah1,Wk -> vmcnt(2)
  STG_A(0, 0, 0);
  STG_A(0, 0, 1);
  STG_K(0, 0);
  STG_V(0, 0);
  asm volatile("s_waitcnt vmcnt(2)" ::: "memory");
  __builtin_amdgcn_sched_barrier(0);
  __builtin_amdgcn_s_barrier();
  __builtin_amdgcn_sched_barrier(0);
  for (int t = 0; t < 8; ++t) {
    const int cb = t & 1, nb = cb ^ 1, tn = t + 1;
    const bool nl = (t != 7);              // not-last
    short8 afA[4][2], afB[4][2], kf[2][2], vf[2][2];
    // ---- ph0: ds {A m0-3, Wk} ; stage Ah0(t+1) ; MFMA K m0-3 ----
#pragma unroll
    for (int m = 0; m < 4; ++m)
#pragma unroll
      for (int ks = 0; ks < 2; ++ks)
        afA[m][ks] = *(const short8*)&lA[cb][(wr*128 + m*16 + li)*64
                                            + (((ks*4 + lk) ^ (li & 7))*8)];
#pragma unroll
    for (int c = 0; c < 2; ++c)
#pragma unroll
      for (int ks = 0; ks < 2; ++ks)
        kf[c][ks] = *(const short8*)&lK[cb][(wn*32 + c*16 + li)*64
                                            + (((ks*4 + lk) ^ (li & 7))*8)];
    if (nl) STG_A(nb, tn, 0);
    PH_ENTER();
#pragma unroll
    for (int m = 0; m < 4; ++m)
#pragma unroll
      for (int c = 0; c < 2; ++c)
#pragma unroll
        for (int ks = 0; ks < 2; ++ks)
          ak[m][c] = mfma16(kf[c][ks], afA[m][ks], ak[m][c]);
    PH_EXIT_VM(nl);                        // drains current Wv (for ph1)
    // ---- ph1: ds {Wv} ; stage Ah1(t+1) ; MFMA V m0-3 ----
#pragma unroll
    for (int c = 0; c < 2; ++c)
#pragma unroll
      for (int ks = 0; ks < 2; ++ks)
        vf[c][ks] = *(const short8*)&lV[cb][(wn*32 + c*16 + li)*64
                                            + (((ks*4 + lk) ^ (li & 7))*8)];
    if (nl) STG_A(nb, tn, 1);
    PH_ENTER();
#pragma unroll
    for (int m = 0; m < 4; ++m)
#pragma unroll
      for (int c = 0; c < 2; ++c)
#pragma unroll
        for (int ks = 0; ks < 2; ++ks)
          av[m][c] = mfma16(afA[m][ks], vf[c][ks], av[m][c]);
    PH_EXIT();
    // ---- ph2: ds {A m4-7} ; stage Wk(t+1) ; MFMA K m4-7 ----
#pragma unroll
    for (int m = 0; m < 4; ++m)
#pragma unroll
      for (int ks = 0; ks < 2; ++ks)
        afB[m][ks] = *(const short8*)&lA[cb][(wr*128 + (m + 4)*16 + li)*64
                                            + (((ks*4 + lk) ^ (li & 7))*8)];
    if (nl) STG_K(nb, tn);
    PH_ENTER();
#pragma unroll
    for (int m = 0; m < 4; ++m)
#pragma unroll
      for (int c = 0; c < 2; ++c)
#pragma unroll
        for (int ks = 0; ks < 2; ++ks)
          ak[m + 4][c] = mfma16(kf[c][ks], afB[m][ks], ak[m + 4][c]);
    PH_EXIT();
    // ---- ph3: stage Wv(t+1) ; MFMA V m4-7 ; vmcnt(2) [t+1 Ah0/Ah1/Wk in] --
    if (nl) STG_V(nb, tn);
    PH_ENTER();
#pragma unroll
    for (int m = 0; m < 4; ++m)
#pragma unroll
      for (int c = 0; c < 2; ++c)
#pragma unroll
        for (int ks = 0; ks < 2; ++ks)
          av[m + 4][c] = mfma16(afB[m][ks], vf[c][ks], av[m + 4][c]);
    PH_EXIT_VM(nl);
  }
#undef STG_A
#undef STG_K
#undef STG_V
#undef PH_ENTER
#undef PH_EXIT
#undef PH_EXIT_VM
  // packed epilogue (R12): Ck rows via swapped-K mapping, CvT cols via av
#pragma unroll
  for (int m = 0; m < 8; ++m)
#pragma unroll
    for (int c = 0; c < 2; ++c) {
      {
        int row = bm + wr*128 + m*16 + li;
        int c0  = bn + wn*32 + c*16 + lk*4;
        f32x4 vk = ak[m][c];
        union { u16 o[4]; short4v v4; } ou;
#pragma unroll
        for (int r = 0; r < 4; ++r) ou.o[r] = f2b(vk[r]);
        *(short4v*)&Ck[(size_t)row * Dd + c0] = ou.v4;
      }
      {
        int col = bn + wn*32 + c*16 + li;
        int r0  = bm + wr*128 + m*16 + lk*4;
        f32x4 vv = av[m][c];
        union { u16 o[4]; short4v v4; } ou;
#pragma unroll
        for (int r = 0; r < 4; ++r) ou.o[r] = f2b(vv[r]);
        *(short4v*)&CvT[(size_t)col * BN + r0] = ou.v4;
      }
    }
}

// ---------------- GEMM 64x64 (small M): operands from global, packed epilogue
// EP: 0 = bf16 out; 1 = f32 out + residual; 2 = bf16 out + bias + relu;
//     3 = f32 out + bias + residual
template<int EP>
__global__ __launch_bounds__(256) void gemm64(const u16* __restrict__ A,
    const u16* __restrict__ Bw, void* __restrict__ Cp,
    const float* __restrict__ bias, const float* __restrict__ res,
    int N, int K) {
  const int lane = threadIdx.x & 63, wid = threadIdx.x >> 6;
  const int wr = wid >> 1, wc = wid & 1;
  const int bm = blockIdx.y * 64, bn = blockIdx.x * 64;
  const int li = lane & 15, lk = lane >> 4;
  f32x4 acc[2][2] = {};
  const u16* Ap = A  + (size_t)(bm + wr*32 + li) * K + lk*8;
  const u16* Bp = Bw + (size_t)(bn + wc*32 + li) * K + lk*8;
#pragma unroll 4
  for (int k0 = 0; k0 < K; k0 += 32) {
    short8 af[2], bf[2];
    af[0] = *(const short8*)(Ap + k0);
    af[1] = *(const short8*)(Ap + (size_t)16*K + k0);
    bf[0] = *(const short8*)(Bp + k0);
    bf[1] = *(const short8*)(Bp + (size_t)16*K + k0);
#pragma unroll
    for (int m = 0; m < 2; ++m)
#pragma unroll
      for (int nn2 = 0; nn2 < 2; ++nn2)
        acc[m][nn2] = mfma16(bf[nn2], af[m], acc[m][nn2]);   // swapped
  }
#pragma unroll
  for (int m = 0; m < 2; ++m)
#pragma unroll
    for (int nn2 = 0; nn2 < 2; ++nn2) {
      int row = bm + wr*32 + m*16 + li;
      int c0  = bn + wc*32 + nn2*16 + lk*4;
      size_t off = (size_t)row * N + c0;
      f32x4 v = acc[m][nn2];
      if constexpr (EP == 0) {
        union { u16 o[4]; short4v v4; } ou;
#pragma unroll
        for (int r = 0; r < 4; ++r) ou.o[r] = f2b(v[r]);
        *(short4v*)&((u16*)Cp)[off] = ou.v4;
      } else if constexpr (EP == 1) {
        float4 rr = *(const float4*)&res[off];
        float4 o = {v[0] + rr.x, v[1] + rr.y, v[2] + rr.z, v[3] + rr.w};
        *(float4*)&((float*)Cp)[off] = o;
      } else if constexpr (EP == 2) {
        float4 bb = *(const float4*)&bias[c0];
        union { u16 o[4]; short4v v4; } ou;
        float x0 = v[0] + bb.x, x1 = v[1] + bb.y, x2 = v[2] + bb.z, x3 = v[3] + bb.w;
        ou.o[0] = f2b(x0 > 0.f ? x0 : 0.f); ou.o[1] = f2b(x1 > 0.f ? x1 : 0.f);
        ou.o[2] = f2b(x2 > 0.f ? x2 : 0.f); ou.o[3] = f2b(x3 > 0.f ? x3 : 0.f);
        *(short4v*)&((u16*)Cp)[off] = ou.v4;
      } else {
        float4 bb = *(const float4*)&bias[c0];
        float4 rr = *(const float4*)&res[off];
        float4 o = {v[0] + bb.x + rr.x, v[1] + bb.y + rr.y,
                    v[2] + bb.z + rr.z, v[3] + bb.w + rr.w};
        *(float4*)&((float*)Cp)[off] = o;
      }
    }
}

// ---------------- FUSED attention v2: register softmax, 2 blocks/CU ----------
__global__ __launch_bounds__(512, 4) void attn_f(const u16* __restrict__ q,
    const u16* __restrict__ kk, const u16* __restrict__ vT,
    float* __restrict__ rowsum, float* __restrict__ Tpart,
    float* __restrict__ attn_mean) {
  const int js = blockIdx.x, b = blockIdx.y;
  const int tid = threadIdx.x, lane = tid & 63, h = tid >> 6;
  __shared__ float redM[8][64];
  __shared__ float redS[8][64];
  __shared__ u16 P2[8][16][72];
  const int li = lane & 15, lk = lane >> 4;
  const size_t BN = (size_t)Bb * Nn;
  const u16* qb = q + (((size_t)b*16 + li)*8 + h)*64 + lk*8;
  short8 a0 = *(const short8*)qb;
  short8 a1 = *(const short8*)(qb + 32);
  f32x4 apv[4] = {};   // apv[n]: D rows = d (n*16+lk*4+r), D cols = i (li)
  float rs_acc[4] = {0.f, 0.f, 0.f, 0.f};
  for (int t2 = 0; t2 < 4; ++t2) {
    const int j0 = js * 256 + t2 * 64;
    f32x4 dt[4];
#pragma unroll
    for (int n = 0; n < 4; ++n) {
      const u16* kb = kk + ((size_t)b*Nn + j0 + n*16 + li)*Dd + h*64 + lk*8;
      f32x4 acc = {};
      acc = mfma16(a0, *(const short8*)kb, acc);
      acc = mfma16(a1, *(const short8*)(kb + 32), acc);
#pragma unroll
      for (int r = 0; r < 4; ++r) dt[n][r] = acc[r] * SCALE;
    }
#pragma unroll
    for (int n = 0; n < 4; ++n) {
      float v = fmaxf(fmaxf(dt[n][0], dt[n][1]), fmaxf(dt[n][2], dt[n][3]));
      v = fmaxf(v, __shfl_xor(v, 16));
      v = fmaxf(v, __shfl_xor(v, 32));
      if (lk == 0) redM[h][n*16 + li] = v;
    }
    __syncthreads();
    float M[4];
#pragma unroll
    for (int n = 0; n < 4; ++n) {
      float m2 = redM[0][n*16 + li];
#pragma unroll
      for (int p = 1; p < 8; ++p) m2 = fmaxf(m2, redM[p][n*16 + li]);
      M[n] = m2;
    }
#pragma unroll
    for (int n = 0; n < 4; ++n) {
      float s = 0.f;
#pragma unroll
      for (int r = 0; r < 4; ++r) { dt[n][r] = __expf(dt[n][r] - M[n]); s += dt[n][r]; }
      s += __shfl_xor(s, 16);
      s += __shfl_xor(s, 32);
      if (lk == 0) redS[h][n*16 + li] = s;
    }
    __syncthreads();
#pragma unroll
    for (int n = 0; n < 4; ++n) {
      float s2 = redS[0][n*16 + li];
#pragma unroll
      for (int p = 1; p < 8; ++p) s2 += redS[p][n*16 + li];
      float inv = 1.f / s2;
#pragma unroll
      for (int r = 0; r < 4; ++r) dt[n][r] = dt[n][r] * inv + EPSR;  // attn+EPS
    }
#pragma unroll
    for (int n = 0; n < 4; ++n)
#pragma unroll
      for (int r = 0; r < 4; ++r)
        P2[h][lk*4 + r][n*16 + li] = f2b(dt[n][r]);
#pragma unroll
    for (int r = 0; r < 4; ++r) {
      float v = dt[0][r] + dt[1][r] + dt[2][r] + dt[3][r];
      v += __shfl_xor(v, 1); v += __shfl_xor(v, 2);
      v += __shfl_xor(v, 4); v += __shfl_xor(v, 8);
      rs_acc[r] += v;
    }
    short8 pa0 = *(const short8*)&P2[h][li][lk*8];
    short8 pa1 = *(const short8*)&P2[h][li][32 + lk*8];
#pragma unroll
    for (int n = 0; n < 4; ++n) {
      const u16* vb = vT + (size_t)(h*64 + n*16 + li)*BN + (size_t)b*Nn + j0 + lk*8;
      apv[n] = mfma16(*(const short8*)vb, pa0, apv[n]);
      apv[n] = mfma16(*(const short8*)(vb + 32), pa1, apv[n]);
    }
    if (attn_mean != nullptr) {
      __syncthreads();
      int j = tid & 63;
#pragma unroll
      for (int ii = 0; ii < 2; ++ii) {
        int i = (tid >> 6) + ii*8;
        float sm = 0.f;
#pragma unroll
        for (int hh = 0; hh < 8; ++hh) sm += b2f(P2[hh][i][j]);
        attn_mean[((size_t)b*16 + i)*Nn + j0 + j] = sm * 0.125f - EPSR;
      }
      __syncthreads();
    }
  }
  float* Tout = Tpart + (((size_t)js * Bb + b) * 8 + h) * 16 * 64;
#pragma unroll
  for (int n = 0; n < 4; ++n) {
    float4 o = {apv[n][0], apv[n][1], apv[n][2], apv[n][3]};
    *(float4*)&Tout[(size_t)li * 64 + n*16 + lk*4] = o;
  }
  if (li == 0)
#pragma unroll
    for (int r = 0; r < 4; ++r)
      atomicAdd(&rowsum[b*128 + (lk*4 + r)*8 + h], rs_acc[r]);
}

// combine partials + renormalize: updb[(b*16+i)*512 + h*64+d]
__global__ void upd_c(const float* __restrict__ Tpart,
    const float* __restrict__ rs, u16* __restrict__ updb) {
  int idx = blockIdx.x * 256 + threadIdx.x;   // 262144 total
  int o = idx & 511, bi = idx >> 9;
  int b = bi >> 4, i = bi & 15;
  int h = o >> 6, d = o & 63;
  size_t base = (((size_t)b * 8 + h) * 16 + i) * 64 + d;
  const size_t stride = (size_t)Bb * 8 * 16 * 64;
  float t = 0.f;
#pragma unroll
  for (int p = 0; p < JS; ++p) t += Tpart[base + p * stride];
  updb[idx] = f2b(t / rs[b * 128 + i * 8 + h]);
}

// ---------------- small utility kernels --------------------------------------
__global__ void cvt_w(const float* __restrict__ s, u16* __restrict__ d, int n) {
  int i = blockIdx.x*256 + threadIdx.x;
  if (i < n) d[i] = f2b(s[i]);
}
// tiled transpose+convert: d[C][R] = bf16(s[R][C]^T)
__global__ __launch_bounds__(256) void tr_cvt(const float* __restrict__ s,
    u16* __restrict__ d, int R, int C) {
  __shared__ u16 t[32][33];
  const int c0 = blockIdx.x*32, r0 = blockIdx.y*32;
  const int tr = threadIdx.x >> 3, tc4 = (threadIdx.x & 7)*4;
  float4 v = *(const float4*)&s[(size_t)(r0+tr)*C + c0 + tc4];
  t[tr][tc4+0] = f2b(v.x); t[tr][tc4+1] = f2b(v.y);
  t[tr][tc4+2] = f2b(v.z); t[tr][tc4+3] = f2b(v.w);
  __syncthreads();
  const int oc = threadIdx.x >> 3, or4 = (threadIdx.x & 7)*4;
  union { u16 o[4]; short4v v4; } ou;
#pragma unroll
  for (int e = 0; e < 4; ++e) ou.o[e] = t[or4+e][oc];
  *(short4v*)&d[(size_t)(c0+oc)*R + r0 + or4] = ou.v4;
}
__global__ void copy_f32v4(const float* __restrict__ s, float* __restrict__ d, int n4) {
  int i = blockIdx.x*256 + threadIdx.x;
  if (i < n4) ((float4*)d)[i] = ((const float4*)s)[i];
}

extern "C" void kernel_launch(void* const* d_in, const int* in_sizes, int n_in,
                              void* d_out, int out_size, void* d_ws, size_t ws_size,
                              hipStream_t stream) {
  (void)in_sizes; (void)n_in; (void)out_size; (void)ws_size;
  const float* inputs  = (const float*)d_in[0];
  const float* cond    = (const float*)d_in[1];
  const float* ln_in_g = (const float*)d_in[2];
  const float* ln_in_b = (const float*)d_in[3];
  const float* Wk = (const float*)d_in[4];
  const float* Wv = (const float*)d_in[5];
  const float* Wq = (const float*)d_in[6];
  const float* Wo = (const float*)d_in[7];
  const float* ln_s_g = (const float*)d_in[8];
  const float* ln_s_b = (const float*)d_in[9];
  const float* ln_f_g = (const float*)d_in[10];
  const float* ln_f_b = (const float*)d_in[11];
  const float* W1 = (const float*)d_in[12];
  const float* b1 = (const float*)d_in[13];
  const float* W2 = (const float*)d_in[14];
  const float* b2 = (const float*)d_in[15];
  float* out_slots = (float*)d_out;
  float* out_amean = (float*)d_out + (size_t)Bb*NSs*Dd;

  char* w = (char*)d_ws;
  auto alloc = [&](size_t bytes) {
    char* p = w; w += (bytes + 255) & ~(size_t)255; return p;
  };
  u16*  xn    = (u16*)alloc((size_t)Bb*Nn*Dd*2);
  u16*  kbuf  = (u16*)alloc((size_t)Bb*Nn*Dd*2);
  u16*  vT    = (u16*)alloc((size_t)Bb*Nn*Dd*2);   // [512][B*N]
  float* Tpart = (float*)alloc((size_t)JS*Bb*8*16*64*4);  // [js][b][h][i][d]
  float* slots = (float*)alloc((size_t)Bb*NSs*Dd*4);
  u16*  qb    = (u16*)alloc((size_t)Bb*NSs*Dd*2);
  u16*  snb   = (u16*)alloc((size_t)Bb*NSs*Dd*2);
  u16*  s2nb  = (u16*)alloc((size_t)Bb*NSs*Dd*2);
  u16*  h1b   = (u16*)alloc((size_t)Bb*NSs*DFF*2);
  u16*  updb  = (u16*)alloc((size_t)Bb*NSs*Dd*2);
  float* rowsum = (float*)alloc((size_t)Bb*128*3*4);   // one per iteration
  u16*  wkb = (u16*)alloc(262144*2);
  u16*  wvb = (u16*)alloc(262144*2);
  u16*  wqb = (u16*)alloc(262144*2);
  u16*  wob = (u16*)alloc(262144*2);
  u16*  w1t = (u16*)alloc((size_t)1048576*2);
  u16*  w2t = (u16*)alloc((size_t)1048576*2);

  // weights -> bf16 (W1/W2 transposed so B-operand is [out,K] row-major)
  cvt_w<<<1024, 256, 0, stream>>>(Wk, wkb, 262144);
  cvt_w<<<1024, 256, 0, stream>>>(Wv, wvb, 262144);
  cvt_w<<<1024, 256, 0, stream>>>(Wq, wqb, 262144);
  cvt_w<<<1024, 256, 0, stream>>>(Wo, wob, 262144);
  tr_cvt<<<dim3(64, 16), 256, 0, stream>>>(W1, w1t, 512, 2048);
  tr_cvt<<<dim3(16, 64), 256, 0, stream>>>(W2, w2t, 2048, 512);
  // slots <- conditioning; rowsum <- 0 (all 3 iterations)
  copy_f32v4<<<256, 256, 0, stream>>>(cond, slots, 65536);
  (void)hipMemsetAsync(rowsum, 0, (size_t)Bb*128*3*4, stream);
  // x = LN(inputs) -> bf16
  ln_rows<<<Bb*Nn/4, 256, 0, stream>>>(inputs, ln_in_g, ln_in_b, xn, Bb*Nn);
  // fused 8-phase: k = x @ Wk^T [B*N,512] and vT = (x @ Wv^T)^T [512, B*N]
  gemm_kv<<<2048, 512, 0, stream>>>(xn, wkb, wvb, kbuf, vT);

  for (int it = 0; it < 3; ++it) {
    float* rsp = rowsum + (size_t)it * Bb * 128;
    ln_rows<<<128, 256, 0, stream>>>(slots, ln_s_g, ln_s_b, snb, Bb*NSs);
    gemm64<0><<<dim3(8, 8), 256, 0, stream>>>(snb, wqb, qb, nullptr, nullptr, 512, 512);
    attn_f<<<dim3(JS, Bb), 512, 0, stream>>>(qb, kbuf, vT, rsp, Tpart,
                                             it == 2 ? out_amean : nullptr);
    upd_c<<<1024, 256, 0, stream>>>(Tpart, rsp, updb);
    gemm64<1><<<dim3(8, 8), 256, 0, stream>>>(updb, wob, slots, nullptr, slots, 512, 512);
    ln_rows<<<128, 256, 0, stream>>>(slots, ln_f_g, ln_f_b, s2nb, Bb*NSs);
    gemm64<2><<<dim3(32, 8), 256, 0, stream>>>(s2nb, w1t, h1b, b1, nullptr, 2048, 512);
    gemm64<3><<<dim3(8, 8), 256, 0, stream>>>(h1b, w2t, slots, b2, slots, 512, 2048);
  }
  copy_f32v4<<<256, 256, 0, stream>>>(slots, out_slots, 65536);
}